// Round 8
// baseline (440.841 us; speedup 1.0000x reference)
//
#include <hip/hip_runtime.h>

#define AS1 __attribute__((address_space(1)))
#define AS3 __attribute__((address_space(3)))

typedef __bf16 bf16;
typedef __bf16 bf16x8 __attribute__((ext_vector_type(8)));
typedef float f32x4 __attribute__((ext_vector_type(4)));

__device__ __forceinline__ void gld_lds16(const bf16* g, bf16* l) {
    __builtin_amdgcn_global_load_lds((const AS1 void*)g, (AS3 void*)l, 16, 0, 0);
}

// ---------------- fp32 -> bf16 cast ----------------
__global__ void cvt4_kernel(const float4* __restrict__ in, ushort4* __restrict__ out, int n4) {
    const int i = blockIdx.x * 256 + threadIdx.x;
    if (i >= n4) return;
    const float4 v = in[i];
    ushort4 r;
    r.x = __builtin_bit_cast(unsigned short, (bf16)v.x);
    r.y = __builtin_bit_cast(unsigned short, (bf16)v.y);
    r.z = __builtin_bit_cast(unsigned short, (bf16)v.z);
    r.w = __builtin_bit_cast(unsigned short, (bf16)v.w);
    out[i] = r;
}

// ---------------- GEMM, counted-vmcnt 3-slot ring, conflict-free swizzled LDS ----------------
// C[M,N] = A[M,K] * W[N,K]^T, row-major K-contiguous, mfma 16x16x32 bf16.
// Block tile 128x256, 256 threads (4 waves, 1M x 4N), per-wave output 128x64
// (8 M-frags x 4 N-frags, acc = 128 VGPR). BK=32.
// LDS: ring of 3 slots (A[128][32] 8KB + B[256][32] 16KB = 24KB/slot, 72KB total
// -> 2 blocks/CU; independent block barriers give cross-block pipe overlap).
// Tile t reads slot t%3 while tile t+2 stages into slot (t+2)%3=(t-1)%3 whose
// readers finished at tile t-1's end barrier. End-of-tile: s_waitcnt vmcnt(6)
// (6 = one tile's stage issues/thread; never 0 until the 2-tile tail) + s_barrier.
// Swizzle: 64B rows = 4 x 16B slots; slot' = slot ^ ((row>>1)&3). Linear
// global_load_lds dest + inverse-permuted GLOBAL source; reads apply the same
// XOR -> each 16-lane phase of ds_read_b128 covers all 8 bank groups exactly 2x
// (2-way = free, m136). Source stays 64B-line coalesced (slots permute in-line).
template <bool OUTF32>
__launch_bounds__(256, 2)
__global__ void gemm_ring_kernel(const bf16* __restrict__ A, const bf16* __restrict__ W,
                                 void* __restrict__ Cout, int M, int N, int K) {
    __shared__ __align__(16) bf16 Asl[3][128 * 32];
    __shared__ __align__(16) bf16 Bsl[3][256 * 32];

    const int tn = blockIdx.x * 256;
    const int tm = blockIdx.y * 128;
    const int tid = threadIdx.x;
    const int wave = tid >> 6;
    const int lane = tid & 63;
    const int laneR = lane & 15;
    const int laneS = lane >> 4;
    const int wnB = wave * 64;                  // wave N offset within 256
    const int NT = K >> 5;                      // K-tiles of 32
    const int sofs = (laneS ^ ((laneR >> 1) & 3)) << 3;   // swizzled slot offset (bf16 units)

    auto stage = [&](int t) {
        const int slot = t % 3;
        const int k0 = t << 5;
#pragma unroll
        for (int iss = 0; iss < 2; ++iss) {     // A: 512 chunks of 16B
            const int c = iss * 256 + wave * 64 + lane;
            const int row = c >> 2;
            const int sg = (c & 3) ^ ((row >> 1) & 3);
            gld_lds16(A + (size_t)(tm + row) * K + k0 + sg * 8,
                      &Asl[slot][iss * 2048 + wave * 512]);
        }
#pragma unroll
        for (int iss = 0; iss < 4; ++iss) {     // B: 1024 chunks of 16B
            const int c = iss * 256 + wave * 64 + lane;
            const int row = c >> 2;
            const int sg = (c & 3) ^ ((row >> 1) & 3);
            gld_lds16(W + (size_t)(tn + row) * K + k0 + sg * 8,
                      &Bsl[slot][iss * 2048 + wave * 512]);
        }
    };

    f32x4 acc[8][4] = {};

    // prologue: stage tiles 0,1; wait own tile-0 issues done; barrier
    stage(0); stage(1);
    asm volatile("s_waitcnt vmcnt(6)" ::: "memory");
    __builtin_amdgcn_sched_barrier(0);
    __builtin_amdgcn_s_barrier();
    __builtin_amdgcn_sched_barrier(0);

    for (int t = 0; t < NT; ++t) {
        const int slot = t % 3;
        if (t + 2 < NT) stage(t + 2);           // into slot (t-1)%3: readers done

        bf16x8 af[8], bfr[4];
#pragma unroll
        for (int nf = 0; nf < 4; ++nf)
            bfr[nf] = *(const bf16x8*)&Bsl[slot][(wnB + nf * 16 + laneR) * 32 + sofs];
#pragma unroll
        for (int mf = 0; mf < 8; ++mf)
            af[mf] = *(const bf16x8*)&Asl[slot][(mf * 16 + laneR) * 32 + sofs];

        __builtin_amdgcn_s_setprio(1);
#pragma unroll
        for (int mf = 0; mf < 8; ++mf)
#pragma unroll
            for (int nf = 0; nf < 4; ++nf)
                acc[mf][nf] = __builtin_amdgcn_mfma_f32_16x16x32_bf16(af[mf], bfr[nf], acc[mf][nf], 0, 0, 0);
        __builtin_amdgcn_s_setprio(0);

        __builtin_amdgcn_sched_barrier(0);
        if (t + 2 < NT) asm volatile("s_waitcnt vmcnt(6)" ::: "memory");
        else            asm volatile("s_waitcnt vmcnt(0)" ::: "memory");
        __builtin_amdgcn_sched_barrier(0);
        __builtin_amdgcn_s_barrier();
        __builtin_amdgcn_sched_barrier(0);
    }

    // epilogue: C/D layout col=lane&15, row=(lane>>4)*4+rr
    const int rbase = laneS * 4;
#pragma unroll
    for (int mf = 0; mf < 8; ++mf)
#pragma unroll
        for (int nf = 0; nf < 4; ++nf)
#pragma unroll
            for (int rr = 0; rr < 4; ++rr) {
                const size_t row = (size_t)tm + mf * 16 + rbase + rr;
                const size_t col = (size_t)tn + wnB + nf * 16 + laneR;
                if constexpr (OUTF32) ((float*)Cout)[row * N + col] = acc[mf][nf][rr];
                else                  ((bf16*)Cout)[row * N + col] = (bf16)acc[mf][nf][rr];
            }
    (void)M;
}

// ---------------- RoPE on q (pre-scaled by log2e/sqrt(D)) and k; layout -> [h][s][d] ----------------
__global__ void rope_qk_kernel(const bf16* __restrict__ C, bf16* __restrict__ Qr, bf16* __restrict__ Kr) {
    const int idx = blockIdx.x * 256 + threadIdx.x;
    const int NQ = 2048 * 32 * 64;
    const float QSC = 0.12751743561884394f;        // (1/sqrt(128)) * log2(e)
    const float LN1E4_64 = 0.14391156831212787f;   // ln(10000)/64
    if (idx < NQ) {
        const int f = idx & 63;
        const int t = idx >> 6;
        const int h = t & 31;
        const int s = t >> 5;
        const float x1 = (float)C[(size_t)s * 6144 + h * 128 + f];
        const float x2 = (float)C[(size_t)s * 6144 + h * 128 + f + 64];
        const float th = s * expf(-LN1E4_64 * (float)f);
        const float cs = cosf(th), sn = sinf(th);
        bf16* dst = Qr + ((size_t)h * 2048 + s) * 128 + f;
        dst[0]  = (bf16)((x1 * cs - x2 * sn) * QSC);
        dst[64] = (bf16)((x2 * cs + x1 * sn) * QSC);
    } else {
        const int i2 = idx - NQ;
        const int f = i2 & 63;
        const int t = i2 >> 6;
        const int h = t & 7;
        const int s = t >> 3;
        const float x1 = (float)C[(size_t)s * 6144 + 4096 + h * 128 + f];
        const float x2 = (float)C[(size_t)s * 6144 + 4096 + h * 128 + f + 64];
        const float th = s * expf(-LN1E4_64 * (float)f);
        const float cs = cosf(th), sn = sinf(th);
        bf16* dst = Kr + ((size_t)h * 2048 + s) * 128 + f;
        dst[0]  = (bf16)(x1 * cs - x2 * sn);
        dst[64] = (bf16)(x2 * cs + x1 * sn);
    }
}

// ---------------- V transpose: C_qkv v-cols -> Vt[hkv][d=128][s=2048] ----------------
__global__ void transpose_v_kernel(const bf16* __restrict__ C, bf16* __restrict__ Vt) {
    __shared__ __align__(16) unsigned short t[64][136];
    const int hkv = blockIdx.x >> 5;
    const int st = blockIdx.x & 31;
    const int s0 = st * 64;
    const int tid = threadIdx.x;
#pragma unroll
    for (int it = 0; it < 4; ++it) {
        const int l = it * 2048 + tid * 8;
        const int r = l >> 7, c = l & 127;
        *(bf16x8*)&t[r][c] = *(const bf16x8*)&C[(size_t)(s0 + r) * 6144 + 5120 + hkv * 128 + c];
    }
    __syncthreads();
#pragma unroll
    for (int it = 0; it < 8; ++it) {
        const int o = it * 1024 + tid * 4;
        const int d = o >> 6, j = o & 63;
        ushort4 pk;
        pk.x = t[j + 0][d];
        pk.y = t[j + 1][d];
        pk.z = t[j + 2][d];
        pk.w = t[j + 3][d];
        *(ushort4*)&Vt[((size_t)hkv * 128 + d) * 2048 + s0 + j] = pk;
    }
}

// ---------------- causal GQA flash attention, equal-work persistent blocks (R6, frozen) ----------------
__launch_bounds__(256, 1)
__global__ void flash_attn_kernel(const bf16* __restrict__ Qr, const bf16* __restrict__ Kr,
                                  const bf16* __restrict__ Vt, bf16* __restrict__ Aout) {
    __shared__ __align__(16) bf16 Klds[2][128 * 128];   // [kv][d], swizzled, 2x32KB
    __shared__ __align__(16) bf16 Vlds[2][128 * 128];   // [d][kv], swizzled, 2x32KB
    __shared__ __align__(16) char Plds[4][4096];        // per-wave P [32][64] bf16, swizzled

    const int bid = blockIdx.x;
    const int hkv = bid & 7;                 // XCD L2 affinity
    const int r = bid >> 3;                  // 0..31
    const int h = hkv * 4 + (r & 3);
    const int pa = r >> 2;                   // 0..7
    const int qbA = 15 - pa, qbB = pa;       // heavy pass, then light pass (17 tiles total)
    const int tid = threadIdx.x;
    const int wave = tid >> 6, lane = tid & 63;
    const int laneR = lane & 15;
    const int laneS = lane >> 4;
    const int laneK = laneS * 8;
    const int rbase = laneS * 4;

    const bf16* Kh = Kr + (size_t)hkv * 2048 * 128;
    const bf16* Vh = Vt + (size_t)hkv * 128 * 2048;
    char* Pw = Plds[wave];

    auto stageK = [&](int kv0, int buf) {
#pragma unroll
        for (int s = 0; s < 8; ++s) {
            const int chunk = wave * 8 + s;
            const int L = chunk * 64 + lane;
            const int row = L >> 4, sl = L & 15;
            gld_lds16(Kh + (size_t)(kv0 + row) * 128 + ((sl ^ (row & 7)) << 3),
                      &Klds[buf][chunk * 512]);
        }
    };
    auto stageV = [&](int kv0, int buf) {
#pragma unroll
        for (int s = 0; s < 8; ++s) {
            const int chunk = wave * 8 + s;
            const int L = chunk * 64 + lane;
            const int row = L >> 4, sl = L & 15;
            gld_lds16(Vh + (size_t)row * 2048 + kv0 + ((sl ^ (row & 7)) << 3),
                      &Vlds[buf][chunk * 512]);
        }
    };

    int qbcur = qbA;
    int q0w = qbA * 128 + wave * 32;
    int tloc = 0;

    bf16x8 qf[2][4];
    auto loadQ = [&]() {
#pragma unroll
        for (int mi = 0; mi < 2; ++mi)
#pragma unroll
            for (int kc = 0; kc < 4; ++kc)
                qf[mi][kc] = *(const bf16x8*)&Qr[((size_t)h * 2048 + q0w + mi * 16 + laneR) * 128 + kc * 32 + laneK];
    };
    loadQ();

    f32x4 o[2][8] = {};
    float mrow[2][4], lrow[2][4];
#pragma unroll
    for (int mi = 0; mi < 2; ++mi)
#pragma unroll
        for (int rr = 0; rr < 4; ++rr) { mrow[mi][rr] = -1e30f; lrow[mi][rr] = 0.f; }

    stageK(0, 0);
    stageV(0, 0);
    __syncthreads();

    for (int g = 0; g < 17; ++g) {
        const int buf = g & 1;
        if (g < 16) {
            const int tn = (g + 1 <= qbA) ? (g + 1) : (g - qbA);
            stageK(tn * 128, buf ^ 1);
            stageV(tn * 128, buf ^ 1);
        }
        const int kv0 = tloc * 128;

        f32x4 sc[2][8] = {};
        __builtin_amdgcn_s_setprio(1);
#pragma unroll
        for (int kc = 0; kc < 4; ++kc) {
            bf16x8 kf[8];
#pragma unroll
            for (int j = 0; j < 8; ++j) {
                const int row = j * 16 + laneR;
                kf[j] = *(const bf16x8*)((const char*)Klds[buf] + row * 256 +
                                         ((kc * 64 + laneS * 16) ^ ((row & 7) << 4)));
            }
#pragma unroll
            for (int mi = 0; mi < 2; ++mi)
#pragma unroll
                for (int j = 0; j < 8; ++j)
                    sc[mi][j] = __builtin_amdgcn_mfma_f32_16x16x32_bf16(qf[mi][kc], kf[j], sc[mi][j], 0, 0, 0);
        }
        __builtin_amdgcn_s_setprio(0);

        if (tloc == qbcur) {
#pragma unroll
            for (int mi = 0; mi < 2; ++mi)
#pragma unroll
                for (int j = 0; j < 8; ++j)
#pragma unroll
                    for (int rr = 0; rr < 4; ++rr) {
                        const int qr = q0w + mi * 16 + rbase + rr;
                        const int kr = kv0 + j * 16 + laneR;
                        if (kr > qr) sc[mi][j][rr] = -1e30f;
                    }
        }

#pragma unroll
        for (int mi = 0; mi < 2; ++mi) {
#pragma unroll
            for (int rr = 0; rr < 4; ++rr) {
                float v = sc[mi][0][rr];
#pragma unroll
                for (int j = 1; j < 8; ++j) v = fmaxf(v, sc[mi][j][rr]);
                v = fmaxf(v, __shfl_xor(v, 1, 64));
                v = fmaxf(v, __shfl_xor(v, 2, 64));
                v = fmaxf(v, __shfl_xor(v, 4, 64));
                v = fmaxf(v, __shfl_xor(v, 8, 64));
                float m0 = mrow[mi][rr];
                if (v - m0 > 8.0f) {
                    const float fac = __builtin_exp2f(m0 - v);
                    mrow[mi][rr] = v;
                    m0 = v;
                    lrow[mi][rr] *= fac;
#pragma unroll
                    for (int j = 0; j < 8; ++j) o[mi][j][rr] *= fac;
                }
                float rs = 0.f;
#pragma unroll
                for (int j = 0; j < 8; ++j) {
                    const float p = __builtin_exp2f(sc[mi][j][rr] - m0);
                    sc[mi][j][rr] = p;
                    rs += p;
                }
                rs += __shfl_xor(rs, 1, 64);
                rs += __shfl_xor(rs, 2, 64);
                rs += __shfl_xor(rs, 4, 64);
                rs += __shfl_xor(rs, 8, 64);
                lrow[mi][rr] += rs;
            }
        }

#pragma unroll
        for (int hf = 0; hf < 2; ++hf) {
#pragma unroll
            for (int mi = 0; mi < 2; ++mi)
#pragma unroll
                for (int j = 0; j < 4; ++j)
#pragma unroll
                    for (int rr = 0; rr < 4; ++rr) {
                        const int row = mi * 16 + rbase + rr;
                        *(bf16*)(Pw + row * 128 + ((j * 32 + laneR * 2) ^ ((row & 7) << 4))) =
                            (bf16)sc[mi][hf * 4 + j][rr];
                    }
            __builtin_amdgcn_s_setprio(1);
#pragma unroll
            for (int kc = 0; kc < 2; ++kc) {
                bf16x8 pf[2];
#pragma unroll
                for (int mi = 0; mi < 2; ++mi) {
                    const int row = mi * 16 + laneR;
                    pf[mi] = *(const bf16x8*)(Pw + row * 128 + ((kc * 64 + laneS * 16) ^ ((row & 7) << 4)));
                }
                const int kcg = hf * 2 + kc;
                bf16x8 vf[8];
#pragma unroll
                for (int j = 0; j < 8; ++j) {
                    const int row = j * 16 + laneR;
                    vf[j] = *(const bf16x8*)((const char*)Vlds[buf] + row * 256 +
                                             ((kcg * 64 + laneS * 16) ^ ((row & 7) << 4)));
                }
#pragma unroll
                for (int mi = 0; mi < 2; ++mi)
#pragma unroll
                    for (int j = 0; j < 8; ++j)
                        o[mi][j] = __builtin_amdgcn_mfma_f32_16x16x32_bf16(pf[mi], vf[j], o[mi][j], 0, 0, 0);
            }
            __builtin_amdgcn_s_setprio(0);
        }

        if (tloc == qbcur) {
#pragma unroll
            for (int mi = 0; mi < 2; ++mi) {
                float rinv[4];
#pragma unroll
                for (int rr = 0; rr < 4; ++rr) rinv[rr] = 1.0f / lrow[mi][rr];
#pragma unroll
                for (int j = 0; j < 8; ++j)
#pragma unroll
                    for (int rr = 0; rr < 4; ++rr) {
                        const size_t row = (size_t)q0w + mi * 16 + rbase + rr;
                        Aout[row * 4096 + h * 128 + j * 16 + laneR] = (bf16)(o[mi][j][rr] * rinv[rr]);
                    }
            }
            if (g < 16) {
                qbcur = qbB;
                q0w = qbB * 128 + wave * 32;
                tloc = 0;
                loadQ();
#pragma unroll
                for (int mi = 0; mi < 2; ++mi)
#pragma unroll
                    for (int rr = 0; rr < 4; ++rr) { mrow[mi][rr] = -1e30f; lrow[mi][rr] = 0.f; }
#pragma unroll
                for (int mi = 0; mi < 2; ++mi)
#pragma unroll
                    for (int j = 0; j < 8; ++j)
                        o[mi][j] = f32x4{0.f, 0.f, 0.f, 0.f};
            }
        } else {
            ++tloc;
        }

        __syncthreads();
    }
}

// ---------------- launch ----------------
extern "C" void kernel_launch(void* const* d_in, const int* in_sizes, int n_in,
                              void* d_out, int out_size, void* d_ws, size_t ws_size,
                              hipStream_t stream) {
    const float* hidden = (const float*)d_in[0];
    const float* Wq = (const float*)d_in[1];
    const float* Wk = (const float*)d_in[2];
    const float* Wv = (const float*)d_in[3];
    const float* Wo = (const float*)d_in[4];
    float* out = (float*)d_out;
    char* ws = (char*)d_ws;

    // workspace layout (bytes):
    bf16* hs = (bf16*)(ws + 0);                 // [2048][4096]        16 MiB
    bf16* Wb = (bf16*)(ws + 16777216);          // [10240][4096]       80 MiB (Wq|Wk|Wv|Wo)
    bf16* Cq = (bf16*)(ws + 100663296);         // [2048][6144]        24 MiB
    bf16* Qr = (bf16*)(ws + 125829120);         // [32][2048][128]     16 MiB
    bf16* Kr = (bf16*)(ws + 142606336);         // [8][2048][128]       4 MiB
    bf16* Vt = (bf16*)(ws + 146800640);         // [8][128][2048]       4 MiB
    bf16* At = (bf16*)(ws + 150994944);         // [2048][4096]        16 MiB
    (void)ws_size; (void)in_sizes; (void)n_in; (void)out_size;

    // 1. casts
    cvt4_kernel<<<8192, 256, 0, stream>>>((const float4*)hidden, (ushort4*)hs, 2097152);
    cvt4_kernel<<<16384, 256, 0, stream>>>((const float4*)Wq, (ushort4*)(Wb + 0), 4194304);
    cvt4_kernel<<<4096, 256, 0, stream>>>((const float4*)Wk, (ushort4*)(Wb + 16777216), 1048576);
    cvt4_kernel<<<4096, 256, 0, stream>>>((const float4*)Wv, (ushort4*)(Wb + 20971520), 1048576);
    cvt4_kernel<<<16384, 256, 0, stream>>>((const float4*)Wo, (ushort4*)(Wb + 25165824), 4194304);

    // 2. fused QKV projection: [2048,6144] = hs @ Wqkv^T  (128x256 tiles -> 384 blocks)
    gemm_ring_kernel<false><<<dim3(24, 16), 256, 0, stream>>>(hs, Wb, Cq, 2048, 6144, 4096);

    // 3. RoPE (+transpose to [h][s][d]); q pre-scaled by log2e/sqrt(D)
    rope_qk_kernel<<<20480, 256, 0, stream>>>(Cq, Qr, Kr);

    // 4. V transpose -> [hkv][d][s]
    transpose_v_kernel<<<256, 256, 0, stream>>>(Cq, Vt);

    // 5. causal GQA flash attention -> At [2048][4096] bf16 (256 equal-work blocks)
    flash_attn_kernel<<<256, 256, 0, stream>>>(Qr, Kr, Vt, At);

    // 6. output projection: out = At @ Wo^T (fp32 out)  (128x256 tiles -> 256 blocks)
    gemm_ring_kernel<true><<<dim3(16, 16), 256, 0, stream>>>(At, Wb + 25165824, out, 2048, 4096, 4096);
}

// Round 9
// 363.053 us; speedup vs baseline: 1.2143x; 1.2143x over previous
//
#include <hip/hip_runtime.h>

#define AS1 __attribute__((address_space(1)))
#define AS3 __attribute__((address_space(3)))

typedef __bf16 bf16;
typedef __bf16 bf16x8 __attribute__((ext_vector_type(8)));
typedef float f32x4 __attribute__((ext_vector_type(4)));

__device__ __forceinline__ void gld_lds16(const bf16* g, bf16* l) {
    __builtin_amdgcn_global_load_lds((const AS1 void*)g, (AS3 void*)l, 16, 0, 0);
}

#define SB0 __builtin_amdgcn_sched_barrier(0)
#define BARX do { SB0; __builtin_amdgcn_s_barrier(); SB0; } while (0)

// ---------------- fp32 -> bf16 cast ----------------
__global__ void cvt4_kernel(const float4* __restrict__ in, ushort4* __restrict__ out, int n4) {
    const int i = blockIdx.x * 256 + threadIdx.x;
    if (i >= n4) return;
    const float4 v = in[i];
    ushort4 r;
    r.x = __builtin_bit_cast(unsigned short, (bf16)v.x);
    r.y = __builtin_bit_cast(unsigned short, (bf16)v.y);
    r.z = __builtin_bit_cast(unsigned short, (bf16)v.z);
    r.w = __builtin_bit_cast(unsigned short, (bf16)v.w);
    out[i] = r;
}

// ---------------- 8-phase 256x256 GEMM, counted vmcnt, swizzled LDS ----------------
// C[M,N] = A[M,K] * W[N,K]^T, row-major K-contiguous, mfma 16x16x32 bf16.
// 512 thr = 8 waves (2M x 4N), per-wave out 128x64 (8 Mfrag x 4 Nfrag, acc 128 VGPR).
// BK=64 (2 k-slices of 32). LDS: A dbuf 2x[256][64] + B dbuf 2x[256][64] = 128KB.
// Iteration i: phases P1-P4 compute K-tile u=2i (dbuf0), P5-P8 tile u+1 (dbuf1).
// Quadrants per tile: (mh,nh) = (0,0),(0,1),(1,1),(1,0) -- B[nh1] and A[mh1] reused
// across adjacent phases. Stages (1 half-tile = 128 rows x 64 cols = 2 issues/thread):
//   P1:A1(u+1) P2:B0(u+1) P3:B1(u+1) P4:A0(u+2) P5:A1(u+2) P6:B0(u+2) P7:B1(u+2) P8:A0(u+3)
// Each stage's dest region's last reader finished >=1 barrier before the issue (race-free).
// s_waitcnt vmcnt(2) at P4/P8 end: leaves only the phase's own 2 issues in flight;
// everything the next 4 phases read has landed. Swizzle: 128B rows = 8 x 16B slots,
// slot' = slot ^ (row&7); linear gld_lds dest + inverse-permuted global source; reads
// apply the same XOR -> 8 lanes per slot-group, conflict-free (R8-verified family).
template <bool OUTF32>
__launch_bounds__(512, 2)
__global__ void gemm_8ph_kernel(const bf16* __restrict__ A, const bf16* __restrict__ W,
                                void* __restrict__ Cout, int M, int N, int K) {
    __shared__ __align__(16) bf16 Asl[2][256 * 64];
    __shared__ __align__(16) bf16 Bsl[2][256 * 64];

    const int tn = blockIdx.x * 256;
    const int tm = blockIdx.y * 256;
    const int tid = threadIdx.x;
    const int wave = tid >> 6;
    const int lane = tid & 63;
    const int laneR = lane & 15;
    const int laneS = lane >> 4;
    const int wmB = (wave >> 2) * 128;      // wave M offset within 256
    const int wnB = (wave & 3) * 64;        // wave N offset within 256
    const int NT = K >> 6;                  // K-tiles of 64
    const int NI = NT >> 1;                 // iterations (2 tiles each)

    // stage one half-tile (h = 0/1 -> rows h*128..h*128+127), 2 issues/thread
    auto stageA = [&](int t, int h) {
        if (t >= NT) return;
        const int d = t & 1, k0 = t << 6;
#pragma unroll
        for (int iss = 0; iss < 2; ++iss) {
            const int c = iss * 512 + tid;            // chunk 0..1023 (16B each)
            const int row = c >> 3, sl = c & 7;
            gld_lds16(A + (size_t)(tm + h * 128 + row) * K + k0 + ((sl ^ (row & 7)) << 3),
                      &Asl[d][h * 8192 + (iss * 512 + wave * 64) * 8]);
        }
    };
    auto stageB = [&](int t, int h) {
        if (t >= NT) return;
        const int d = t & 1, k0 = t << 6;
#pragma unroll
        for (int iss = 0; iss < 2; ++iss) {
            const int c = iss * 512 + tid;
            const int row = c >> 3, sl = c & 7;
            gld_lds16(W + (size_t)(tn + h * 128 + row) * K + k0 + ((sl ^ (row & 7)) << 3),
                      &Bsl[d][h * 8192 + (iss * 512 + wave * 64) * 8]);
        }
    };

    bf16x8 aF[8], bF0[4], bF1[4];
    f32x4 acc[8][4] = {};

#define RD_A(d, mh) do { _Pragma("unroll") for (int m = 0; m < 4; ++m) \
    _Pragma("unroll") for (int ks = 0; ks < 2; ++ks) { \
        const int row_ = wmB + (mh) * 64 + m * 16 + laneR; \
        const int sl_ = (ks * 4 + laneS) ^ (row_ & 7); \
        aF[m * 2 + ks] = *(const bf16x8*)&Asl[d][row_ * 64 + sl_ * 8]; } } while (0)

#define RD_B(d, nh, DST) do { _Pragma("unroll") for (int n = 0; n < 2; ++n) \
    _Pragma("unroll") for (int ks = 0; ks < 2; ++ks) { \
        const int row_ = wnB + (nh) * 32 + n * 16 + laneR; \
        const int sl_ = (ks * 4 + laneS) ^ (row_ & 7); \
        DST[n * 2 + ks] = *(const bf16x8*)&Bsl[d][row_ * 64 + sl_ * 8]; } } while (0)

#define MMAQ(mh, nh, BSRC) do { __builtin_amdgcn_s_setprio(1); \
    _Pragma("unroll") for (int m = 0; m < 4; ++m) \
    _Pragma("unroll") for (int n = 0; n < 2; ++n) \
    _Pragma("unroll") for (int ks = 0; ks < 2; ++ks) \
        acc[(mh) * 4 + m][(nh) * 2 + n] = __builtin_amdgcn_mfma_f32_16x16x32_bf16( \
            aF[m * 2 + ks], BSRC[n * 2 + ks], acc[(mh) * 4 + m][(nh) * 2 + n], 0, 0, 0); \
    __builtin_amdgcn_s_setprio(0); } while (0)

    // prologue: tile 0 complete + A0(1); wait all but the trailing half-tile
    stageA(0, 0); stageA(0, 1); stageB(0, 0); stageB(0, 1); stageA(1, 0);
    SB0; asm volatile("s_waitcnt vmcnt(2)" ::: "memory"); BARX;

    for (int i = 0; i < NI; ++i) {
        const int u = i * 2;
        const bool last = (i == NI - 1);
        // P1
        RD_A(0, 0); RD_B(0, 0, bF0); stageA(u + 1, 1);
        BARX; MMAQ(0, 0, bF0); BARX;
        // P2
        RD_B(0, 1, bF1); stageB(u + 1, 0);
        BARX; MMAQ(0, 1, bF1); BARX;
        // P3
        RD_A(0, 1); stageB(u + 1, 1);
        BARX; MMAQ(1, 1, bF1); BARX;
        // P4
        RD_B(0, 0, bF0); stageA(u + 2, 0);
        BARX; MMAQ(1, 0, bF0);
        SB0;
        if (last) asm volatile("s_waitcnt vmcnt(0)" ::: "memory");
        else      asm volatile("s_waitcnt vmcnt(2)" ::: "memory");
        BARX;
        // P5
        RD_A(1, 0); RD_B(1, 0, bF0); stageA(u + 2, 1);
        BARX; MMAQ(0, 0, bF0); BARX;
        // P6
        RD_B(1, 1, bF1); stageB(u + 2, 0);
        BARX; MMAQ(0, 1, bF1); BARX;
        // P7
        RD_A(1, 1); stageB(u + 2, 1);
        BARX; MMAQ(1, 1, bF1); BARX;
        // P8
        RD_B(1, 0, bF0); stageA(u + 3, 0);
        BARX; MMAQ(1, 0, bF0);
        SB0;
        if (last) asm volatile("s_waitcnt vmcnt(0)" ::: "memory");
        else      asm volatile("s_waitcnt vmcnt(2)" ::: "memory");
        BARX;
    }
#undef RD_A
#undef RD_B
#undef MMAQ

    // epilogue: C/D layout col=lane&15, row=(lane>>4)*4+rr
    const int rbase = laneS * 4;
#pragma unroll
    for (int mf = 0; mf < 8; ++mf)
#pragma unroll
        for (int nf = 0; nf < 4; ++nf)
#pragma unroll
            for (int rr = 0; rr < 4; ++rr) {
                const size_t row = (size_t)tm + wmB + mf * 16 + rbase + rr;
                const size_t col = (size_t)tn + wnB + nf * 16 + laneR;
                if constexpr (OUTF32) ((float*)Cout)[row * N + col] = acc[mf][nf][rr];
                else                  ((bf16*)Cout)[row * N + col] = (bf16)acc[mf][nf][rr];
            }
    (void)M;
}

// ---------------- GEMM, R7 counted-vmcnt 4-slot ring (proven; used for O-proj) ----------------
template <int BN, bool OUTF32>
__launch_bounds__(512, 2)
__global__ void gemm8p_kernel(const bf16* __restrict__ A, const bf16* __restrict__ W,
                              void* __restrict__ Cout, int M, int N, int K) {
    constexpr int NF = BN / 64;
    constexpr int IB = BN / 128;
    __shared__ __align__(16) bf16 Asl[4][128 * 32];
    __shared__ __align__(16) bf16 Bsl[4][BN * 32];

    const int tn = blockIdx.x * BN;
    const int tm = blockIdx.y * 128;
    const int tid = threadIdx.x;
    const int wave = tid >> 6;
    const int lane = tid & 63;
    const int laneR = lane & 15;
    const int laneS = lane >> 4;
    const int wmB = (wave >> 2) * 64;
    const int wnB = (wave & 3) * (BN / 4);
    const int NT = K >> 5;

    auto stage = [&](int t) {
        const int slot = t & 3;
        const int k0 = t << 5;
        {
            const int row = tid >> 2, g = tid & 3;
            gld_lds16(A + (size_t)(tm + row) * K + k0 + g * 8, &Asl[slot][wave * 512]);
        }
#pragma unroll
        for (int i = 0; i < IB; ++i) {
            const int row = i * 128 + (tid >> 2), g = tid & 3;
            gld_lds16(W + (size_t)(tn + row) * K + k0 + g * 8,
                      &Bsl[slot][i * 4096 + wave * 512]);
        }
    };

    f32x4 acc[4][NF] = {};

    stage(0); stage(1); stage(2);
    asm volatile("s_waitcnt vmcnt(6)" ::: "memory");
    SB0;
    __builtin_amdgcn_s_barrier();
    SB0;

    for (int t = 0; t < NT; ++t) {
        const int slot = t & 3;
        bf16x8 af[4], bfr[NF];
#pragma unroll
        for (int mf = 0; mf < 4; ++mf)
            af[mf] = *(const bf16x8*)&Asl[slot][(wmB + mf * 16 + laneR) * 32 + laneS * 8];
#pragma unroll
        for (int nf = 0; nf < NF; ++nf)
            bfr[nf] = *(const bf16x8*)&Bsl[slot][(wnB + nf * 16 + laneR) * 32 + laneS * 8];

        if (t + 3 < NT) stage(t + 3);

#pragma unroll
        for (int mf = 0; mf < 4; ++mf)
#pragma unroll
            for (int nf = 0; nf < NF; ++nf)
                acc[mf][nf] = __builtin_amdgcn_mfma_f32_16x16x32_bf16(af[mf], bfr[nf], acc[mf][nf], 0, 0, 0);

        SB0;
        if (t + 3 < NT)      asm volatile("s_waitcnt vmcnt(6)" ::: "memory");
        else if (t + 3 == NT) asm volatile("s_waitcnt vmcnt(3)" ::: "memory");
        else                  asm volatile("s_waitcnt vmcnt(0)" ::: "memory");
        SB0;
        __builtin_amdgcn_s_barrier();
        SB0;
    }

    const int rbase = laneS * 4;
#pragma unroll
    for (int mf = 0; mf < 4; ++mf)
#pragma unroll
        for (int nf = 0; nf < NF; ++nf)
#pragma unroll
            for (int rr = 0; rr < 4; ++rr) {
                const size_t row = (size_t)tm + wmB + mf * 16 + rbase + rr;
                const size_t col = (size_t)tn + wnB + nf * 16 + laneR;
                if constexpr (OUTF32) ((float*)Cout)[row * N + col] = acc[mf][nf][rr];
                else                  ((bf16*)Cout)[row * N + col] = (bf16)acc[mf][nf][rr];
            }
    (void)M;
}

// ---------------- RoPE on q (pre-scaled by log2e/sqrt(D)) and k; layout -> [h][s][d] ----------------
__global__ void rope_qk_kernel(const bf16* __restrict__ C, bf16* __restrict__ Qr, bf16* __restrict__ Kr) {
    const int idx = blockIdx.x * 256 + threadIdx.x;
    const int NQ = 2048 * 32 * 64;
    const float QSC = 0.12751743561884394f;        // (1/sqrt(128)) * log2(e)
    const float LN1E4_64 = 0.14391156831212787f;   // ln(10000)/64
    if (idx < NQ) {
        const int f = idx & 63;
        const int t = idx >> 6;
        const int h = t & 31;
        const int s = t >> 5;
        const float x1 = (float)C[(size_t)s * 6144 + h * 128 + f];
        const float x2 = (float)C[(size_t)s * 6144 + h * 128 + f + 64];
        const float th = s * expf(-LN1E4_64 * (float)f);
        const float cs = cosf(th), sn = sinf(th);
        bf16* dst = Qr + ((size_t)h * 2048 + s) * 128 + f;
        dst[0]  = (bf16)((x1 * cs - x2 * sn) * QSC);
        dst[64] = (bf16)((x2 * cs + x1 * sn) * QSC);
    } else {
        const int i2 = idx - NQ;
        const int f = i2 & 63;
        const int t = i2 >> 6;
        const int h = t & 7;
        const int s = t >> 3;
        const float x1 = (float)C[(size_t)s * 6144 + 4096 + h * 128 + f];
        const float x2 = (float)C[(size_t)s * 6144 + 4096 + h * 128 + f + 64];
        const float th = s * expf(-LN1E4_64 * (float)f);
        const float cs = cosf(th), sn = sinf(th);
        bf16* dst = Kr + ((size_t)h * 2048 + s) * 128 + f;
        dst[0]  = (bf16)(x1 * cs - x2 * sn);
        dst[64] = (bf16)(x2 * cs + x1 * sn);
    }
}

// ---------------- V transpose: C_qkv v-cols -> Vt[hkv][d=128][s=2048] ----------------
__global__ void transpose_v_kernel(const bf16* __restrict__ C, bf16* __restrict__ Vt) {
    __shared__ __align__(16) unsigned short t[64][136];
    const int hkv = blockIdx.x >> 5;
    const int st = blockIdx.x & 31;
    const int s0 = st * 64;
    const int tid = threadIdx.x;
#pragma unroll
    for (int it = 0; it < 4; ++it) {
        const int l = it * 2048 + tid * 8;
        const int r = l >> 7, c = l & 127;
        *(bf16x8*)&t[r][c] = *(const bf16x8*)&C[(size_t)(s0 + r) * 6144 + 5120 + hkv * 128 + c];
    }
    __syncthreads();
#pragma unroll
    for (int it = 0; it < 8; ++it) {
        const int o = it * 1024 + tid * 4;
        const int d = o >> 6, j = o & 63;
        ushort4 pk;
        pk.x = t[j + 0][d];
        pk.y = t[j + 1][d];
        pk.z = t[j + 2][d];
        pk.w = t[j + 3][d];
        *(ushort4*)&Vt[((size_t)hkv * 128 + d) * 2048 + s0 + j] = pk;
    }
}

// ---------------- causal GQA flash attention, equal-work persistent blocks (R6, frozen) ----------------
__launch_bounds__(256, 1)
__global__ void flash_attn_kernel(const bf16* __restrict__ Qr, const bf16* __restrict__ Kr,
                                  const bf16* __restrict__ Vt, bf16* __restrict__ Aout) {
    __shared__ __align__(16) bf16 Klds[2][128 * 128];
    __shared__ __align__(16) bf16 Vlds[2][128 * 128];
    __shared__ __align__(16) char Plds[4][4096];

    const int bid = blockIdx.x;
    const int hkv = bid & 7;
    const int r = bid >> 3;
    const int h = hkv * 4 + (r & 3);
    const int pa = r >> 2;
    const int qbA = 15 - pa, qbB = pa;
    const int tid = threadIdx.x;
    const int wave = tid >> 6, lane = tid & 63;
    const int laneR = lane & 15;
    const int laneS = lane >> 4;
    const int laneK = laneS * 8;
    const int rbase = laneS * 4;

    const bf16* Kh = Kr + (size_t)hkv * 2048 * 128;
    const bf16* Vh = Vt + (size_t)hkv * 128 * 2048;
    char* Pw = Plds[wave];

    auto stageK = [&](int kv0, int buf) {
#pragma unroll
        for (int s = 0; s < 8; ++s) {
            const int chunk = wave * 8 + s;
            const int L = chunk * 64 + lane;
            const int row = L >> 4, sl = L & 15;
            gld_lds16(Kh + (size_t)(kv0 + row) * 128 + ((sl ^ (row & 7)) << 3),
                      &Klds[buf][chunk * 512]);
        }
    };
    auto stageV = [&](int kv0, int buf) {
#pragma unroll
        for (int s = 0; s < 8; ++s) {
            const int chunk = wave * 8 + s;
            const int L = chunk * 64 + lane;
            const int row = L >> 4, sl = L & 15;
            gld_lds16(Vh + (size_t)row * 2048 + kv0 + ((sl ^ (row & 7)) << 3),
                      &Vlds[buf][chunk * 512]);
        }
    };

    int qbcur = qbA;
    int q0w = qbA * 128 + wave * 32;
    int tloc = 0;

    bf16x8 qf[2][4];
    auto loadQ = [&]() {
#pragma unroll
        for (int mi = 0; mi < 2; ++mi)
#pragma unroll
            for (int kc = 0; kc < 4; ++kc)
                qf[mi][kc] = *(const bf16x8*)&Qr[((size_t)h * 2048 + q0w + mi * 16 + laneR) * 128 + kc * 32 + laneK];
    };
    loadQ();

    f32x4 o[2][8] = {};
    float mrow[2][4], lrow[2][4];
#pragma unroll
    for (int mi = 0; mi < 2; ++mi)
#pragma unroll
        for (int rr = 0; rr < 4; ++rr) { mrow[mi][rr] = -1e30f; lrow[mi][rr] = 0.f; }

    stageK(0, 0);
    stageV(0, 0);
    __syncthreads();

    for (int g = 0; g < 17; ++g) {
        const int buf = g & 1;
        if (g < 16) {
            const int tn = (g + 1 <= qbA) ? (g + 1) : (g - qbA);
            stageK(tn * 128, buf ^ 1);
            stageV(tn * 128, buf ^ 1);
        }
        const int kv0 = tloc * 128;

        f32x4 sc[2][8] = {};
        __builtin_amdgcn_s_setprio(1);
#pragma unroll
        for (int kc = 0; kc < 4; ++kc) {
            bf16x8 kf[8];
#pragma unroll
            for (int j = 0; j < 8; ++j) {
                const int row = j * 16 + laneR;
                kf[j] = *(const bf16x8*)((const char*)Klds[buf] + row * 256 +
                                         ((kc * 64 + laneS * 16) ^ ((row & 7) << 4)));
            }
#pragma unroll
            for (int mi = 0; mi < 2; ++mi)
#pragma unroll
                for (int j = 0; j < 8; ++j)
                    sc[mi][j] = __builtin_amdgcn_mfma_f32_16x16x32_bf16(qf[mi][kc], kf[j], sc[mi][j], 0, 0, 0);
        }
        __builtin_amdgcn_s_setprio(0);

        if (tloc == qbcur) {
#pragma unroll
            for (int mi = 0; mi < 2; ++mi)
#pragma unroll
                for (int j = 0; j < 8; ++j)
#pragma unroll
                    for (int rr = 0; rr < 4; ++rr) {
                        const int qr = q0w + mi * 16 + rbase + rr;
                        const int kr = kv0 + j * 16 + laneR;
                        if (kr > qr) sc[mi][j][rr] = -1e30f;
                    }
        }

#pragma unroll
        for (int mi = 0; mi < 2; ++mi) {
#pragma unroll
            for (int rr = 0; rr < 4; ++rr) {
                float v = sc[mi][0][rr];
#pragma unroll
                for (int j = 1; j < 8; ++j) v = fmaxf(v, sc[mi][j][rr]);
                v = fmaxf(v, __shfl_xor(v, 1, 64));
                v = fmaxf(v, __shfl_xor(v, 2, 64));
                v = fmaxf(v, __shfl_xor(v, 4, 64));
                v = fmaxf(v, __shfl_xor(v, 8, 64));
                float m0 = mrow[mi][rr];
                if (v - m0 > 8.0f) {
                    const float fac = __builtin_exp2f(m0 - v);
                    mrow[mi][rr] = v;
                    m0 = v;
                    lrow[mi][rr] *= fac;
#pragma unroll
                    for (int j = 0; j < 8; ++j) o[mi][j][rr] *= fac;
                }
                float rs = 0.f;
#pragma unroll
                for (int j = 0; j < 8; ++j) {
                    const float p = __builtin_exp2f(sc[mi][j][rr] - m0);
                    sc[mi][j][rr] = p;
                    rs += p;
                }
                rs += __shfl_xor(rs, 1, 64);
                rs += __shfl_xor(rs, 2, 64);
                rs += __shfl_xor(rs, 4, 64);
                rs += __shfl_xor(rs, 8, 64);
                lrow[mi][rr] += rs;
            }
        }

#pragma unroll
        for (int hf = 0; hf < 2; ++hf) {
#pragma unroll
            for (int mi = 0; mi < 2; ++mi)
#pragma unroll
                for (int j = 0; j < 4; ++j)
#pragma unroll
                    for (int rr = 0; rr < 4; ++rr) {
                        const int row = mi * 16 + rbase + rr;
                        *(bf16*)(Pw + row * 128 + ((j * 32 + laneR * 2) ^ ((row & 7) << 4))) =
                            (bf16)sc[mi][hf * 4 + j][rr];
                    }
            __builtin_amdgcn_s_setprio(1);
#pragma unroll
            for (int kc = 0; kc < 2; ++kc) {
                bf16x8 pf[2];
#pragma unroll
                for (int mi = 0; mi < 2; ++mi) {
                    const int row = mi * 16 + laneR;
                    pf[mi] = *(const bf16x8*)(Pw + row * 128 + ((kc * 64 + laneS * 16) ^ ((row & 7) << 4)));
                }
                const int kcg = hf * 2 + kc;
                bf16x8 vf[8];
#pragma unroll
                for (int j = 0; j < 8; ++j) {
                    const int row = j * 16 + laneR;
                    vf[j] = *(const bf16x8*)((const char*)Vlds[buf] + row * 256 +
                                             ((kcg * 64 + laneS * 16) ^ ((row & 7) << 4)));
                }
#pragma unroll
                for (int mi = 0; mi < 2; ++mi)
#pragma unroll
                    for (int j = 0; j < 8; ++j)
                        o[mi][j] = __builtin_amdgcn_mfma_f32_16x16x32_bf16(pf[mi], vf[j], o[mi][j], 0, 0, 0);
            }
            __builtin_amdgcn_s_setprio(0);
        }

        if (tloc == qbcur) {
#pragma unroll
            for (int mi = 0; mi < 2; ++mi) {
                float rinv[4];
#pragma unroll
                for (int rr = 0; rr < 4; ++rr) rinv[rr] = 1.0f / lrow[mi][rr];
#pragma unroll
                for (int j = 0; j < 8; ++j)
#pragma unroll
                    for (int rr = 0; rr < 4; ++rr) {
                        const size_t row = (size_t)q0w + mi * 16 + rbase + rr;
                        Aout[row * 4096 + h * 128 + j * 16 + laneR] = (bf16)(o[mi][j][rr] * rinv[rr]);
                    }
            }
            if (g < 16) {
                qbcur = qbB;
                q0w = qbB * 128 + wave * 32;
                tloc = 0;
                loadQ();
#pragma unroll
                for (int mi = 0; mi < 2; ++mi)
#pragma unroll
                    for (int rr = 0; rr < 4; ++rr) { mrow[mi][rr] = -1e30f; lrow[mi][rr] = 0.f; }
#pragma unroll
                for (int mi = 0; mi < 2; ++mi)
#pragma unroll
                    for (int j = 0; j < 8; ++j)
                        o[mi][j] = f32x4{0.f, 0.f, 0.f, 0.f};
            }
        } else {
            ++tloc;
        }

        __syncthreads();
    }
}

// ---------------- launch ----------------
extern "C" void kernel_launch(void* const* d_in, const int* in_sizes, int n_in,
                              void* d_out, int out_size, void* d_ws, size_t ws_size,
                              hipStream_t stream) {
    const float* hidden = (const float*)d_in[0];
    const float* Wq = (const float*)d_in[1];
    const float* Wk = (const float*)d_in[2];
    const float* Wv = (const float*)d_in[3];
    const float* Wo = (const float*)d_in[4];
    float* out = (float*)d_out;
    char* ws = (char*)d_ws;

    // workspace layout (bytes):
    bf16* hs = (bf16*)(ws + 0);                 // [2048][4096]        16 MiB
    bf16* Wb = (bf16*)(ws + 16777216);          // [10240][4096]       80 MiB (Wq|Wk|Wv|Wo)
    bf16* Cq = (bf16*)(ws + 100663296);         // [2048][6144]        24 MiB
    bf16* Qr = (bf16*)(ws + 125829120);         // [32][2048][128]     16 MiB
    bf16* Kr = (bf16*)(ws + 142606336);         // [8][2048][128]       4 MiB
    bf16* Vt = (bf16*)(ws + 146800640);         // [8][128][2048]       4 MiB
    bf16* At = (bf16*)(ws + 150994944);         // [2048][4096]        16 MiB
    (void)ws_size; (void)in_sizes; (void)n_in; (void)out_size;

    // 1. casts
    cvt4_kernel<<<8192, 256, 0, stream>>>((const float4*)hidden, (ushort4*)hs, 2097152);
    cvt4_kernel<<<16384, 256, 0, stream>>>((const float4*)Wq, (ushort4*)(Wb + 0), 4194304);
    cvt4_kernel<<<4096, 256, 0, stream>>>((const float4*)Wk, (ushort4*)(Wb + 16777216), 1048576);
    cvt4_kernel<<<4096, 256, 0, stream>>>((const float4*)Wv, (ushort4*)(Wb + 20971520), 1048576);
    cvt4_kernel<<<16384, 256, 0, stream>>>((const float4*)Wo, (ushort4*)(Wb + 25165824), 4194304);

    // 2. fused QKV projection: [2048,6144] = hs @ Wqkv^T  (256x256 8-phase -> 192 blocks)
    gemm_8ph_kernel<false><<<dim3(24, 8), 512, 0, stream>>>(hs, Wb, Cq, 2048, 6144, 4096);

    // 3. RoPE (+transpose to [h][s][d]); q pre-scaled by log2e/sqrt(D)
    rope_qk_kernel<<<20480, 256, 0, stream>>>(Cq, Qr, Kr);

    // 4. V transpose -> [hkv][d][s]
    transpose_v_kernel<<<256, 256, 0, stream>>>(Cq, Vt);

    // 5. causal GQA flash attention -> At [2048][4096] bf16 (256 equal-work blocks)
    flash_attn_kernel<<<256, 256, 0, stream>>>(Qr, Kr, Vt, At);

    // 6. output projection: out = At @ Wo^T (fp32 out)  (R7 ring, 128x256 -> 256 blocks)
    gemm8p_kernel<256, true><<<dim3(16, 16), 512, 0, stream>>>(At, Wb + 25165824, out, 2048, 4096, 4096);
}

// Round 10
// 351.054 us; speedup vs baseline: 1.2558x; 1.0342x over previous
//
#include <hip/hip_runtime.h>

#define AS1 __attribute__((address_space(1)))
#define AS3 __attribute__((address_space(3)))

typedef __bf16 bf16;
typedef __bf16 bf16x8 __attribute__((ext_vector_type(8)));
typedef float f32x4 __attribute__((ext_vector_type(4)));

__device__ __forceinline__ void gld_lds16(const bf16* g, bf16* l) {
    __builtin_amdgcn_global_load_lds((const AS1 void*)g, (AS3 void*)l, 16, 0, 0);
}

#define SB0 __builtin_amdgcn_sched_barrier(0)
#define BARX do { SB0; __builtin_amdgcn_s_barrier(); SB0; } while (0)

// ---------------- fused fp32 -> bf16 cast (all 5 tensors, one launch) ----------------
// float4-range partition: hidden 2097152 | Wq 4194304 | Wk 1048576 | Wv 1048576 | Wo 4194304
__global__ void cvt_all_kernel(const float4* __restrict__ h, const float4* __restrict__ wq,
                               const float4* __restrict__ wk, const float4* __restrict__ wv,
                               const float4* __restrict__ wo, ushort4* __restrict__ hs,
                               ushort4* __restrict__ wb) {
    const int i = blockIdx.x * 256 + threadIdx.x;   // 0 .. 12582911
    const float4* src;
    ushort4* dst;
    if (i < 2097152)      { src = h  + i;             dst = hs + i; }
    else if (i < 6291456) { src = wq + (i - 2097152); dst = wb + (i - 2097152); }
    else if (i < 7340032) { src = wk + (i - 6291456); dst = wb + 4194304 + (i - 6291456); }
    else if (i < 8388608) { src = wv + (i - 7340032); dst = wb + 5242880 + (i - 7340032); }
    else                  { src = wo + (i - 8388608); dst = wb + 6291456 + (i - 8388608); }
    const float4 v = *src;
    ushort4 r;
    r.x = __builtin_bit_cast(unsigned short, (bf16)v.x);
    r.y = __builtin_bit_cast(unsigned short, (bf16)v.y);
    r.z = __builtin_bit_cast(unsigned short, (bf16)v.z);
    r.w = __builtin_bit_cast(unsigned short, (bf16)v.w);
    *dst = r;
}

// ---------------- 8-phase 256x256 GEMM, counted vmcnt, swizzled LDS (R9, frozen) ----------------
template <bool OUTF32>
__launch_bounds__(512, 2)
__global__ void gemm_8ph_kernel(const bf16* __restrict__ A, const bf16* __restrict__ W,
                                void* __restrict__ Cout, int M, int N, int K) {
    __shared__ __align__(16) bf16 Asl[2][256 * 64];
    __shared__ __align__(16) bf16 Bsl[2][256 * 64];

    const int tn = blockIdx.x * 256;
    const int tm = blockIdx.y * 256;
    const int tid = threadIdx.x;
    const int wave = tid >> 6;
    const int lane = tid & 63;
    const int laneR = lane & 15;
    const int laneS = lane >> 4;
    const int wmB = (wave >> 2) * 128;
    const int wnB = (wave & 3) * 64;
    const int NT = K >> 6;
    const int NI = NT >> 1;

    auto stageA = [&](int t, int h) {
        if (t >= NT) return;
        const int d = t & 1, k0 = t << 6;
#pragma unroll
        for (int iss = 0; iss < 2; ++iss) {
            const int c = iss * 512 + tid;
            const int row = c >> 3, sl = c & 7;
            gld_lds16(A + (size_t)(tm + h * 128 + row) * K + k0 + ((sl ^ (row & 7)) << 3),
                      &Asl[d][h * 8192 + (iss * 512 + wave * 64) * 8]);
        }
    };
    auto stageB = [&](int t, int h) {
        if (t >= NT) return;
        const int d = t & 1, k0 = t << 6;
#pragma unroll
        for (int iss = 0; iss < 2; ++iss) {
            const int c = iss * 512 + tid;
            const int row = c >> 3, sl = c & 7;
            gld_lds16(W + (size_t)(tn + h * 128 + row) * K + k0 + ((sl ^ (row & 7)) << 3),
                      &Bsl[d][h * 8192 + (iss * 512 + wave * 64) * 8]);
        }
    };

    bf16x8 aF[8], bF0[4], bF1[4];
    f32x4 acc[8][4] = {};

#define RD_A(d, mh) do { _Pragma("unroll") for (int m = 0; m < 4; ++m) \
    _Pragma("unroll") for (int ks = 0; ks < 2; ++ks) { \
        const int row_ = wmB + (mh) * 64 + m * 16 + laneR; \
        const int sl_ = (ks * 4 + laneS) ^ (row_ & 7); \
        aF[m * 2 + ks] = *(const bf16x8*)&Asl[d][row_ * 64 + sl_ * 8]; } } while (0)

#define RD_B(d, nh, DST) do { _Pragma("unroll") for (int n = 0; n < 2; ++n) \
    _Pragma("unroll") for (int ks = 0; ks < 2; ++ks) { \
        const int row_ = wnB + (nh) * 32 + n * 16 + laneR; \
        const int sl_ = (ks * 4 + laneS) ^ (row_ & 7); \
        DST[n * 2 + ks] = *(const bf16x8*)&Bsl[d][row_ * 64 + sl_ * 8]; } } while (0)

#define MMAQ(mh, nh, BSRC) do { __builtin_amdgcn_s_setprio(1); \
    _Pragma("unroll") for (int m = 0; m < 4; ++m) \
    _Pragma("unroll") for (int n = 0; n < 2; ++n) \
    _Pragma("unroll") for (int ks = 0; ks < 2; ++ks) \
        acc[(mh) * 4 + m][(nh) * 2 + n] = __builtin_amdgcn_mfma_f32_16x16x32_bf16( \
            aF[m * 2 + ks], BSRC[n * 2 + ks], acc[(mh) * 4 + m][(nh) * 2 + n], 0, 0, 0); \
    __builtin_amdgcn_s_setprio(0); } while (0)

    stageA(0, 0); stageA(0, 1); stageB(0, 0); stageB(0, 1); stageA(1, 0);
    SB0; asm volatile("s_waitcnt vmcnt(2)" ::: "memory"); BARX;

    for (int i = 0; i < NI; ++i) {
        const int u = i * 2;
        const bool last = (i == NI - 1);
        RD_A(0, 0); RD_B(0, 0, bF0); stageA(u + 1, 1);
        BARX; MMAQ(0, 0, bF0); BARX;
        RD_B(0, 1, bF1); stageB(u + 1, 0);
        BARX; MMAQ(0, 1, bF1); BARX;
        RD_A(0, 1); stageB(u + 1, 1);
        BARX; MMAQ(1, 1, bF1); BARX;
        RD_B(0, 0, bF0); stageA(u + 2, 0);
        BARX; MMAQ(1, 0, bF0);
        SB0;
        if (last) asm volatile("s_waitcnt vmcnt(0)" ::: "memory");
        else      asm volatile("s_waitcnt vmcnt(2)" ::: "memory");
        BARX;
        RD_A(1, 0); RD_B(1, 0, bF0); stageA(u + 2, 1);
        BARX; MMAQ(0, 0, bF0); BARX;
        RD_B(1, 1, bF1); stageB(u + 2, 0);
        BARX; MMAQ(0, 1, bF1); BARX;
        RD_A(1, 1); stageB(u + 2, 1);
        BARX; MMAQ(1, 1, bF1); BARX;
        RD_B(1, 0, bF0); stageA(u + 3, 0);
        BARX; MMAQ(1, 0, bF0);
        SB0;
        if (last) asm volatile("s_waitcnt vmcnt(0)" ::: "memory");
        else      asm volatile("s_waitcnt vmcnt(2)" ::: "memory");
        BARX;
    }
#undef RD_A
#undef RD_B
#undef MMAQ

    const int rbase = laneS * 4;
#pragma unroll
    for (int mf = 0; mf < 8; ++mf)
#pragma unroll
        for (int nf = 0; nf < 4; ++nf)
#pragma unroll
            for (int rr = 0; rr < 4; ++rr) {
                const size_t row = (size_t)tm + wmB + mf * 16 + rbase + rr;
                const size_t col = (size_t)tn + wnB + nf * 16 + laneR;
                if constexpr (OUTF32) ((float*)Cout)[row * N + col] = acc[mf][nf][rr];
                else                  ((bf16*)Cout)[row * N + col] = (bf16)acc[mf][nf][rr];
            }
    (void)M;
}

// ---------------- GEMM, R7 counted-vmcnt 4-slot ring + R8-validated conflict-free swizzle ----------------
// 64B LDS rows = 4 x 16B slots; slot' = slot ^ ((row>>1)&3). Linear gld_lds dest +
// inverse-permuted global source; reads apply the same XOR (R8: 0 bank conflicts).
template <int BN, bool OUTF32>
__launch_bounds__(512, 2)
__global__ void gemm8p_kernel(const bf16* __restrict__ A, const bf16* __restrict__ W,
                              void* __restrict__ Cout, int M, int N, int K) {
    constexpr int NF = BN / 64;
    constexpr int IB = BN / 128;
    __shared__ __align__(16) bf16 Asl[4][128 * 32];
    __shared__ __align__(16) bf16 Bsl[4][BN * 32];

    const int tn = blockIdx.x * BN;
    const int tm = blockIdx.y * 128;
    const int tid = threadIdx.x;
    const int wave = tid >> 6;
    const int lane = tid & 63;
    const int laneR = lane & 15;
    const int laneS = lane >> 4;
    const int wmB = (wave >> 2) * 64;
    const int wnB = (wave & 3) * (BN / 4);
    const int NT = K >> 5;
    const int sofs = (laneS ^ ((laneR >> 1) & 3)) << 3;   // swizzled read offset (bf16)

    auto stage = [&](int t) {
        const int slot = t & 3;
        const int k0 = t << 5;
        {
            const int row = tid >> 2, g = tid & 3;
            const int sg = g ^ ((row >> 1) & 3);
            gld_lds16(A + (size_t)(tm + row) * K + k0 + sg * 8, &Asl[slot][wave * 512]);
        }
#pragma unroll
        for (int i = 0; i < IB; ++i) {
            const int row = i * 128 + (tid >> 2), g = tid & 3;
            const int sg = g ^ ((row >> 1) & 3);
            gld_lds16(W + (size_t)(tn + row) * K + k0 + sg * 8,
                      &Bsl[slot][i * 4096 + wave * 512]);
        }
    };

    f32x4 acc[4][NF] = {};

    stage(0); stage(1); stage(2);
    asm volatile("s_waitcnt vmcnt(6)" ::: "memory");
    SB0;
    __builtin_amdgcn_s_barrier();
    SB0;

    for (int t = 0; t < NT; ++t) {
        const int slot = t & 3;
        bf16x8 af[4], bfr[NF];
#pragma unroll
        for (int mf = 0; mf < 4; ++mf)
            af[mf] = *(const bf16x8*)&Asl[slot][(wmB + mf * 16 + laneR) * 32 + sofs];
#pragma unroll
        for (int nf = 0; nf < NF; ++nf)
            bfr[nf] = *(const bf16x8*)&Bsl[slot][(wnB + nf * 16 + laneR) * 32 + sofs];

        if (t + 3 < NT) stage(t + 3);

#pragma unroll
        for (int mf = 0; mf < 4; ++mf)
#pragma unroll
            for (int nf = 0; nf < NF; ++nf)
                acc[mf][nf] = __builtin_amdgcn_mfma_f32_16x16x32_bf16(af[mf], bfr[nf], acc[mf][nf], 0, 0, 0);

        SB0;
        if (t + 3 < NT)       asm volatile("s_waitcnt vmcnt(6)" ::: "memory");
        else if (t + 3 == NT) asm volatile("s_waitcnt vmcnt(3)" ::: "memory");
        else                  asm volatile("s_waitcnt vmcnt(0)" ::: "memory");
        SB0;
        __builtin_amdgcn_s_barrier();
        SB0;
    }

    const int rbase = laneS * 4;
#pragma unroll
    for (int mf = 0; mf < 4; ++mf)
#pragma unroll
        for (int nf = 0; nf < NF; ++nf)
#pragma unroll
            for (int rr = 0; rr < 4; ++rr) {
                const size_t row = (size_t)tm + wmB + mf * 16 + rbase + rr;
                const size_t col = (size_t)tn + wnB + nf * 16 + laneR;
                if constexpr (OUTF32) ((float*)Cout)[row * N + col] = acc[mf][nf][rr];
                else                  ((bf16*)Cout)[row * N + col] = (bf16)acc[mf][nf][rr];
            }
    (void)M;
}

// ---------------- RoPE cos/sin table gen: [2048][64] each, f32 ----------------
__global__ void rope_table_kernel(float* __restrict__ ct, float* __restrict__ st) {
    const int idx = blockIdx.x * 256 + threadIdx.x;   // 131072
    const int f = idx & 63;
    const int s = idx >> 6;
    const float th = s * expf(-0.14391156831212787f * (float)f);
    ct[idx] = cosf(th);
    st[idx] = sinf(th);
}

// ---------------- RoPE on q (pre-scaled by log2e/sqrt(D)) and k; table-based ----------------
__global__ void rope_qk_kernel(const bf16* __restrict__ C, bf16* __restrict__ Qr, bf16* __restrict__ Kr,
                               const float* __restrict__ ct, const float* __restrict__ st) {
    const int idx = blockIdx.x * 256 + threadIdx.x;
    const int NQ = 2048 * 32 * 64;
    const float QSC = 0.12751743561884394f;        // (1/sqrt(128)) * log2(e)
    if (idx < NQ) {
        const int f = idx & 63;
        const int t = idx >> 6;
        const int h = t & 31;
        const int s = t >> 5;
        const float x1 = (float)C[(size_t)s * 6144 + h * 128 + f];
        const float x2 = (float)C[(size_t)s * 6144 + h * 128 + f + 64];
        const float cs = ct[(s << 6) + f], sn = st[(s << 6) + f];
        bf16* dst = Qr + ((size_t)h * 2048 + s) * 128 + f;
        dst[0]  = (bf16)((x1 * cs - x2 * sn) * QSC);
        dst[64] = (bf16)((x2 * cs + x1 * sn) * QSC);
    } else {
        const int i2 = idx - NQ;
        const int f = i2 & 63;
        const int t = i2 >> 6;
        const int h = t & 7;
        const int s = t >> 3;
        const float x1 = (float)C[(size_t)s * 6144 + 4096 + h * 128 + f];
        const float x2 = (float)C[(size_t)s * 6144 + 4096 + h * 128 + f + 64];
        const float cs = ct[(s << 6) + f], sn = st[(s << 6) + f];
        bf16* dst = Kr + ((size_t)h * 2048 + s) * 128 + f;
        dst[0]  = (bf16)(x1 * cs - x2 * sn);
        dst[64] = (bf16)(x2 * cs + x1 * sn);
    }
}

// ---------------- V transpose: C_qkv v-cols -> Vt[hkv][d=128][s=2048] ----------------
__global__ void transpose_v_kernel(const bf16* __restrict__ C, bf16* __restrict__ Vt) {
    __shared__ __align__(16) unsigned short t[64][136];
    const int hkv = blockIdx.x >> 5;
    const int st = blockIdx.x & 31;
    const int s0 = st * 64;
    const int tid = threadIdx.x;
#pragma unroll
    for (int it = 0; it < 4; ++it) {
        const int l = it * 2048 + tid * 8;
        const int r = l >> 7, c = l & 127;
        *(bf16x8*)&t[r][c] = *(const bf16x8*)&C[(size_t)(s0 + r) * 6144 + 5120 + hkv * 128 + c];
    }
    __syncthreads();
#pragma unroll
    for (int it = 0; it < 8; ++it) {
        const int o = it * 1024 + tid * 4;
        const int d = o >> 6, j = o & 63;
        ushort4 pk;
        pk.x = t[j + 0][d];
        pk.y = t[j + 1][d];
        pk.z = t[j + 2][d];
        pk.w = t[j + 3][d];
        *(ushort4*)&Vt[((size_t)hkv * 128 + d) * 2048 + s0 + j] = pk;
    }
}

// ---------------- causal GQA flash attention, equal-work persistent blocks (R6, frozen) ----------------
__launch_bounds__(256, 1)
__global__ void flash_attn_kernel(const bf16* __restrict__ Qr, const bf16* __restrict__ Kr,
                                  const bf16* __restrict__ Vt, bf16* __restrict__ Aout) {
    __shared__ __align__(16) bf16 Klds[2][128 * 128];
    __shared__ __align__(16) bf16 Vlds[2][128 * 128];
    __shared__ __align__(16) char Plds[4][4096];

    const int bid = blockIdx.x;
    const int hkv = bid & 7;
    const int r = bid >> 3;
    const int h = hkv * 4 + (r & 3);
    const int pa = r >> 2;
    const int qbA = 15 - pa, qbB = pa;
    const int tid = threadIdx.x;
    const int wave = tid >> 6, lane = tid & 63;
    const int laneR = lane & 15;
    const int laneS = lane >> 4;
    const int laneK = laneS * 8;
    const int rbase = laneS * 4;

    const bf16* Kh = Kr + (size_t)hkv * 2048 * 128;
    const bf16* Vh = Vt + (size_t)hkv * 128 * 2048;
    char* Pw = Plds[wave];

    auto stageK = [&](int kv0, int buf) {
#pragma unroll
        for (int s = 0; s < 8; ++s) {
            const int chunk = wave * 8 + s;
            const int L = chunk * 64 + lane;
            const int row = L >> 4, sl = L & 15;
            gld_lds16(Kh + (size_t)(kv0 + row) * 128 + ((sl ^ (row & 7)) << 3),
                      &Klds[buf][chunk * 512]);
        }
    };
    auto stageV = [&](int kv0, int buf) {
#pragma unroll
        for (int s = 0; s < 8; ++s) {
            const int chunk = wave * 8 + s;
            const int L = chunk * 64 + lane;
            const int row = L >> 4, sl = L & 15;
            gld_lds16(Vh + (size_t)row * 2048 + kv0 + ((sl ^ (row & 7)) << 3),
                      &Vlds[buf][chunk * 512]);
        }
    };

    int qbcur = qbA;
    int q0w = qbA * 128 + wave * 32;
    int tloc = 0;

    bf16x8 qf[2][4];
    auto loadQ = [&]() {
#pragma unroll
        for (int mi = 0; mi < 2; ++mi)
#pragma unroll
            for (int kc = 0; kc < 4; ++kc)
                qf[mi][kc] = *(const bf16x8*)&Qr[((size_t)h * 2048 + q0w + mi * 16 + laneR) * 128 + kc * 32 + laneK];
    };
    loadQ();

    f32x4 o[2][8] = {};
    float mrow[2][4], lrow[2][4];
#pragma unroll
    for (int mi = 0; mi < 2; ++mi)
#pragma unroll
        for (int rr = 0; rr < 4; ++rr) { mrow[mi][rr] = -1e30f; lrow[mi][rr] = 0.f; }

    stageK(0, 0);
    stageV(0, 0);
    __syncthreads();

    for (int g = 0; g < 17; ++g) {
        const int buf = g & 1;
        if (g < 16) {
            const int tn = (g + 1 <= qbA) ? (g + 1) : (g - qbA);
            stageK(tn * 128, buf ^ 1);
            stageV(tn * 128, buf ^ 1);
        }
        const int kv0 = tloc * 128;

        f32x4 sc[2][8] = {};
        __builtin_amdgcn_s_setprio(1);
#pragma unroll
        for (int kc = 0; kc < 4; ++kc) {
            bf16x8 kf[8];
#pragma unroll
            for (int j = 0; j < 8; ++j) {
                const int row = j * 16 + laneR;
                kf[j] = *(const bf16x8*)((const char*)Klds[buf] + row * 256 +
                                         ((kc * 64 + laneS * 16) ^ ((row & 7) << 4)));
            }
#pragma unroll
            for (int mi = 0; mi < 2; ++mi)
#pragma unroll
                for (int j = 0; j < 8; ++j)
                    sc[mi][j] = __builtin_amdgcn_mfma_f32_16x16x32_bf16(qf[mi][kc], kf[j], sc[mi][j], 0, 0, 0);
        }
        __builtin_amdgcn_s_setprio(0);

        if (tloc == qbcur) {
#pragma unroll
            for (int mi = 0; mi < 2; ++mi)
#pragma unroll
                for (int j = 0; j < 8; ++j)
#pragma unroll
                    for (int rr = 0; rr < 4; ++rr) {
                        const int qr = q0w + mi * 16 + rbase + rr;
                        const int kr = kv0 + j * 16 + laneR;
                        if (kr > qr) sc[mi][j][rr] = -1e30f;
                    }
        }

#pragma unroll
        for (int mi = 0; mi < 2; ++mi) {
#pragma unroll
            for (int rr = 0; rr < 4; ++rr) {
                float v = sc[mi][0][rr];
#pragma unroll
                for (int j = 1; j < 8; ++j) v = fmaxf(v, sc[mi][j][rr]);
                v = fmaxf(v, __shfl_xor(v, 1, 64));
                v = fmaxf(v, __shfl_xor(v, 2, 64));
                v = fmaxf(v, __shfl_xor(v, 4, 64));
                v = fmaxf(v, __shfl_xor(v, 8, 64));
                float m0 = mrow[mi][rr];
                if (v - m0 > 8.0f) {
                    const float fac = __builtin_exp2f(m0 - v);
                    mrow[mi][rr] = v;
                    m0 = v;
                    lrow[mi][rr] *= fac;
#pragma unroll
                    for (int j = 0; j < 8; ++j) o[mi][j][rr] *= fac;
                }
                float rs = 0.f;
#pragma unroll
                for (int j = 0; j < 8; ++j) {
                    const float p = __builtin_exp2f(sc[mi][j][rr] - m0);
                    sc[mi][j][rr] = p;
                    rs += p;
                }
                rs += __shfl_xor(rs, 1, 64);
                rs += __shfl_xor(rs, 2, 64);
                rs += __shfl_xor(rs, 4, 64);
                rs += __shfl_xor(rs, 8, 64);
                lrow[mi][rr] += rs;
            }
        }

#pragma unroll
        for (int hf = 0; hf < 2; ++hf) {
#pragma unroll
            for (int mi = 0; mi < 2; ++mi)
#pragma unroll
                for (int j = 0; j < 4; ++j)
#pragma unroll
                    for (int rr = 0; rr < 4; ++rr) {
                        const int row = mi * 16 + rbase + rr;
                        *(bf16*)(Pw + row * 128 + ((j * 32 + laneR * 2) ^ ((row & 7) << 4))) =
                            (bf16)sc[mi][hf * 4 + j][rr];
                    }
            __builtin_amdgcn_s_setprio(1);
#pragma unroll
            for (int kc = 0; kc < 2; ++kc) {
                bf16x8 pf[2];
#pragma unroll
                for (int mi = 0; mi < 2; ++mi) {
                    const int row = mi * 16 + laneR;
                    pf[mi] = *(const bf16x8*)(Pw + row * 128 + ((kc * 64 + laneS * 16) ^ ((row & 7) << 4)));
                }
                const int kcg = hf * 2 + kc;
                bf16x8 vf[8];
#pragma unroll
                for (int j = 0; j < 8; ++j) {
                    const int row = j * 16 + laneR;
                    vf[j] = *(const bf16x8*)((const char*)Vlds[buf] + row * 256 +
                                             ((kcg * 64 + laneS * 16) ^ ((row & 7) << 4)));
                }
#pragma unroll
                for (int mi = 0; mi < 2; ++mi)
#pragma unroll
                    for (int j = 0; j < 8; ++j)
                        o[mi][j] = __builtin_amdgcn_mfma_f32_16x16x32_bf16(pf[mi], vf[j], o[mi][j], 0, 0, 0);
            }
            __builtin_amdgcn_s_setprio(0);
        }

        if (tloc == qbcur) {
#pragma unroll
            for (int mi = 0; mi < 2; ++mi) {
                float rinv[4];
#pragma unroll
                for (int rr = 0; rr < 4; ++rr) rinv[rr] = 1.0f / lrow[mi][rr];
#pragma unroll
                for (int j = 0; j < 8; ++j)
#pragma unroll
                    for (int rr = 0; rr < 4; ++rr) {
                        const size_t row = (size_t)q0w + mi * 16 + rbase + rr;
                        Aout[row * 4096 + h * 128 + j * 16 + laneR] = (bf16)(o[mi][j][rr] * rinv[rr]);
                    }
            }
            if (g < 16) {
                qbcur = qbB;
                q0w = qbB * 128 + wave * 32;
                tloc = 0;
                loadQ();
#pragma unroll
                for (int mi = 0; mi < 2; ++mi)
#pragma unroll
                    for (int rr = 0; rr < 4; ++rr) { mrow[mi][rr] = -1e30f; lrow[mi][rr] = 0.f; }
#pragma unroll
                for (int mi = 0; mi < 2; ++mi)
#pragma unroll
                    for (int j = 0; j < 8; ++j)
                        o[mi][j] = f32x4{0.f, 0.f, 0.f, 0.f};
            }
        } else {
            ++tloc;
        }

        __syncthreads();
    }
}

// ---------------- launch ----------------
extern "C" void kernel_launch(void* const* d_in, const int* in_sizes, int n_in,
                              void* d_out, int out_size, void* d_ws, size_t ws_size,
                              hipStream_t stream) {
    const float* hidden = (const float*)d_in[0];
    const float* Wq = (const float*)d_in[1];
    const float* Wk = (const float*)d_in[2];
    const float* Wv = (const float*)d_in[3];
    const float* Wo = (const float*)d_in[4];
    float* out = (float*)d_out;
    char* ws = (char*)d_ws;

    // workspace layout (bytes):
    bf16* hs = (bf16*)(ws + 0);                 // [2048][4096]        16 MiB (dead after QKV)
    bf16* Wb = (bf16*)(ws + 16777216);          // [10240][4096]       80 MiB (Wq|Wk|Wv|Wo)
    bf16* Cq = (bf16*)(ws + 100663296);         // [2048][6144]        24 MiB
    bf16* Qr = (bf16*)(ws + 125829120);         // [32][2048][128]     16 MiB
    bf16* Kr = (bf16*)(ws + 142606336);         // [8][2048][128]       4 MiB
    bf16* Vt = (bf16*)(ws + 146800640);         // [8][128][2048]       4 MiB
    bf16* At = (bf16*)(ws + 150994944);         // [2048][4096]        16 MiB
    float* ct = (float*)(ws + 0);               // rope cos table [2048][64] (aliases dead hs)
    float* st = (float*)(ws + 524288);          // rope sin table [2048][64]
    (void)ws_size; (void)in_sizes; (void)n_in; (void)out_size;

    // 1. fused casts (one launch, 12582912 float4)
    cvt_all_kernel<<<49152, 256, 0, stream>>>((const float4*)hidden, (const float4*)Wq,
                                              (const float4*)Wk, (const float4*)Wv,
                                              (const float4*)Wo, (ushort4*)hs, (ushort4*)Wb);

    // 2. fused QKV projection: [2048,6144] = hs @ Wqkv^T  (256x256 8-phase -> 192 blocks)
    gemm_8ph_kernel<false><<<dim3(24, 8), 512, 0, stream>>>(hs, Wb, Cq, 2048, 6144, 4096);

    // 3a. rope tables (hs region is dead now; ~0.3 us)
    rope_table_kernel<<<512, 256, 0, stream>>>(ct, st);

    // 3b. RoPE (+transpose to [h][s][d]); q pre-scaled by log2e/sqrt(D)
    rope_qk_kernel<<<20480, 256, 0, stream>>>(Cq, Qr, Kr, ct, st);

    // 4. V transpose -> [hkv][d][s]
    transpose_v_kernel<<<256, 256, 0, stream>>>(Cq, Vt);

    // 5. causal GQA flash attention -> At [2048][4096] bf16 (256 equal-work blocks)
    flash_attn_kernel<<<256, 256, 0, stream>>>(Qr, Kr, Vt, At);

    // 6. output projection: out = At @ Wo^T (fp32 out)  (R7 ring + swizzle, 128x256 -> 256 blocks)
    gemm8p_kernel<256, true><<<dim3(16, 16), 512, 0, stream>>>(At, Wb + 25165824, out, 2048, 4096, 4096);
}